// Round 1
// baseline (300.840 us; speedup 1.0000x reference)
//
#include <hip/hip_runtime.h>
#include <math.h>

#define BB  32
#define CCH 1024
#define HH  64
#define WW  64
#define JJ  128
#define NP  4
#define HID 128
#define CT  64
#define JT  32

typedef float f4 __attribute__((ext_vector_type(4)));

__device__ __forceinline__ float bilin(const float* pl, float ix, float iy) {
  float x0f = floorf(ix), y0f = floorf(iy);
  float wx1 = ix - x0f, wx0 = 1.0f - wx1;
  float wy1 = iy - y0f, wy0 = 1.0f - wy1;
  int x0 = (int)x0f, y0 = (int)y0f;
  int x1 = x0 + 1, y1 = y0 + 1;
  float v = 0.0f;
  if (y0 >= 0 && y0 < HH) {
    if (x0 >= 0 && x0 < WW) v += pl[y0*WW + x0] * (wx0*wy0);
    if (x1 >= 0 && x1 < WW) v += pl[y0*WW + x1] * (wx1*wy0);
  }
  if (y1 >= 0 && y1 < HH) {
    if (x0 >= 0 && x0 < WW) v += pl[y1*WW + x0] * (wx0*wy1);
    if (x1 >= 0 && x1 < WW) v += pl[y1*WW + x1] * (wx1*wy1);
  }
  return v;
}

// Pass A: seed[b][c][j] = bilinear(features[b,c,:,:], keypoint[b,j])
__global__ __launch_bounds__(256) void k_seed(const float* __restrict__ feat,
                                              const float* __restrict__ kp,
                                              float* __restrict__ seed) {
  int c = blockIdx.x, b = blockIdx.y;
  __shared__ __align__(16) float pl[HH*WW];
  const f4* p4 = (const f4*)(feat + ((size_t)(b*CCH + c)) * (size_t)(HH*WW));
  f4* s4 = (f4*)pl;
  #pragma unroll
  for (int r = 0; r < 4; ++r) s4[threadIdx.x + r*256] = p4[threadIdx.x + r*256];
  __syncthreads();
  int j = threadIdx.x;
  if (j < JJ) {
    float gx = kp[((size_t)b*JJ + j)*2 + 0];
    float gy = kp[((size_t)b*JJ + j)*2 + 1];
    float ix = (gx + 1.0f) * 0.5f * (float)(WW - 1);
    float iy = (gy + 1.0f) * 0.5f * (float)(HH - 1);
    seed[((size_t)(b*CCH + c))*JJ + j] = bilin(pl, ix, iy);
  }
}

// Pass B: partial hidden GEMM. part[ch][b][m][o][j] = sum_{c in half ch} w1[m][o][c]*seed[b][c][j]
__global__ __launch_bounds__(256) void k_mlp(const float* __restrict__ seed,
                                             const float* __restrict__ w_off1,
                                             const float* __restrict__ w_att1,
                                             float* __restrict__ part) {
  int jq = blockIdx.x, ch = blockIdx.y, b = blockIdx.z;
  int j0 = jq * JT;
  int cbase = ch * (CCH/2);
  __shared__ __align__(16) float sW[2][CT][HID];   // [mlp][c][o], 64 KB
  __shared__ __align__(16) float sS[CT][JT];       // [c][j], 8 KB
  int t = threadIdx.x;
  int ocol = t & 31, jrow = t >> 5;                // 32 x 8 thread grid
  int o0 = ocol * 4, jl0 = jrow * 4;
  f4 acc0[4], acc1[4];
  #pragma unroll
  for (int i = 0; i < 4; ++i) { acc0[i] = 0.0f; acc1[i] = 0.0f; }

  for (int ct = 0; ct < (CCH/2)/CT; ++ct) {
    int c0 = cbase + ct * CT;
    // stage S tile: 64c x 32j floats = 512 float4
    #pragma unroll
    for (int r = 0; r < 2; ++r) {
      int i4 = r * 256 + t;
      int cc = i4 >> 3, q = i4 & 7;
      f4 v = *(const f4*)&seed[((size_t)(b*CCH + c0 + cc))*JJ + j0 + q*4];
      *(f4*)&sS[cc][q*4] = v;
    }
    // stage W tiles (transposed to [c][o]): 2 x 128o x 64c = 4096 float4
    #pragma unroll
    for (int r = 0; r < 16; ++r) {
      int idx = r * 256 + t;
      int m = idx >> 11;
      int rem = idx & 2047;
      int o = rem >> 4;
      int ccq = rem & 15;
      const float* wsrc = m ? w_att1 : w_off1;
      f4 v = *(const f4*)&wsrc[(size_t)o*CCH + c0 + ccq*4];
      #pragma unroll
      for (int k = 0; k < 4; ++k) sW[m][ccq*4 + k][o] = v[k];
    }
    __syncthreads();
    #pragma unroll 4
    for (int cc = 0; cc < CT; ++cc) {
      f4 w0 = *(const f4*)&sW[0][cc][o0];
      f4 w1 = *(const f4*)&sW[1][cc][o0];
      f4 s  = *(const f4*)&sS[cc][jl0];
      #pragma unroll
      for (int oi = 0; oi < 4; ++oi) {
        acc0[oi] += s * w0[oi];
        acc1[oi] += s * w1[oi];
      }
    }
    __syncthreads();
  }
  size_t half = (size_t)BB * 2 * HID * JJ;
  #pragma unroll
  for (int oi = 0; oi < 4; ++oi) {
    *(f4*)&part[(size_t)ch*half + (((size_t)(b*2 + 0))*HID + o0 + oi)*JJ + j0 + jl0] = acc0[oi];
    *(f4*)&part[(size_t)ch*half + (((size_t)(b*2 + 1))*HID + o0 + oi)*JJ + j0 + jl0] = acc1[oi];
  }
}

// Pass E: reduce partials + bias + relu, layer2, softmax, new grid coords.
__global__ __launch_bounds__(256) void k_head(const float* __restrict__ part,
                                              const float* __restrict__ kp,
                                              const float* __restrict__ b_off1,
                                              const float* __restrict__ w_off2,
                                              const float* __restrict__ b_off2,
                                              const float* __restrict__ b_att1,
                                              const float* __restrict__ w_att2,
                                              const float* __restrict__ b_att2,
                                              float* __restrict__ grids,
                                              float* __restrict__ attw) {
  int jq = blockIdx.x, b = blockIdx.y;
  int j0 = jq * JT;
  __shared__ float sH[2][HID][JT+1];
  __shared__ float sO[JT][13];
  size_t half = (size_t)BB * 2 * HID * JJ;
  for (int idx = threadIdx.x; idx < 2*HID*JT; idx += 256) {
    int m = idx >> 12;           // /(128*32)
    int rem = idx & 4095;
    int o = rem >> 5, jl = rem & 31;
    size_t base = (((size_t)(b*2 + m))*HID + o)*JJ + j0 + jl;
    float v = part[base] + part[half + base];
    v += (m ? b_att1 : b_off1)[o];
    sH[m][o][jl] = fmaxf(v, 0.0f);
  }
  __syncthreads();
  for (int idx = threadIdx.x; idx < 12*JT; idx += 256) {
    int jl = idx / 12, q = idx % 12;
    int m = (q < 8) ? 0 : 1;
    int p = m ? (q - 8) : q;
    const float* w2 = m ? w_att2 : w_off2;
    float sum = (m ? b_att2 : b_off2)[p];
    for (int o = 0; o < HID; ++o) sum += w2[p*HID + o] * sH[m][o][jl];
    sO[jl][q] = sum;
  }
  __syncthreads();
  if (threadIdx.x < JT) {
    int jl = threadIdx.x, j = j0 + jl;
    float gx = kp[((size_t)b*JJ + j)*2 + 0];
    float gy = kp[((size_t)b*JJ + j)*2 + 1];
    const float sc = 2.0f / 63.0f;
    float a[NP];
    #pragma unroll
    for (int n = 0; n < NP; ++n) {
      grids[(((size_t)b*JJ + j)*NP + n)*2 + 0] = gx + sO[jl][2*n + 0]*sc;
      grids[(((size_t)b*JJ + j)*NP + n)*2 + 1] = gy + sO[jl][2*n + 1]*sc;
      a[n] = sO[jl][8 + n];
    }
    float mx = fmaxf(fmaxf(a[0], a[1]), fmaxf(a[2], a[3]));
    float e[NP], s = 0.0f;
    #pragma unroll
    for (int n = 0; n < NP; ++n) { e[n] = expf(a[n] - mx); s += e[n]; }
    float inv = 1.0f / s;
    #pragma unroll
    for (int n = 0; n < NP; ++n) attw[((size_t)b*JJ + j)*NP + n] = e[n]*inv;
  }
}

// Pass C: fusedT[b][c][j] = sum_n attw[b][j][n] * bilinear(features[b,c], grids[b][j][n])
__global__ __launch_bounds__(256) void k_fuse(const float* __restrict__ feat,
                                              const float* __restrict__ grids,
                                              const float* __restrict__ attw,
                                              float* __restrict__ fusedT) {
  int c = blockIdx.x, b = blockIdx.y;
  __shared__ __align__(16) float pl[HH*WW];
  __shared__ float sG[JJ*NP*2];
  __shared__ float sA[JJ*NP];
  const f4* p4 = (const f4*)(feat + ((size_t)(b*CCH + c)) * (size_t)(HH*WW));
  f4* s4 = (f4*)pl;
  #pragma unroll
  for (int r = 0; r < 4; ++r) s4[threadIdx.x + r*256] = p4[threadIdx.x + r*256];
  const float* gb = grids + (size_t)b*JJ*NP*2;
  const float* ab = attw  + (size_t)b*JJ*NP;
  for (int i = threadIdx.x; i < JJ*NP*2; i += 256) sG[i] = gb[i];
  for (int i = threadIdx.x; i < JJ*NP;   i += 256) sA[i] = ab[i];
  __syncthreads();
  int j = threadIdx.x;
  if (j < JJ) {
    float acc = 0.0f;
    #pragma unroll
    for (int n = 0; n < NP; ++n) {
      float gx = sG[(j*NP + n)*2 + 0];
      float gy = sG[(j*NP + n)*2 + 1];
      float ix = (gx + 1.0f) * 0.5f * (float)(WW - 1);
      float iy = (gy + 1.0f) * 0.5f * (float)(HH - 1);
      acc += sA[j*NP + n] * bilin(pl, ix, iy);
    }
    fusedT[((size_t)(b*CCH + c))*JJ + j] = acc;
  }
}

// Pass D: out[b][j][c] = fusedT[b][c][j]
__global__ __launch_bounds__(256) void k_tr(const float* __restrict__ fusedT,
                                            float* __restrict__ out) {
  int b = blockIdx.z;
  int c0 = blockIdx.x * 32, j0 = blockIdx.y * 32;
  __shared__ float tl[32][33];
  int tx = threadIdx.x & 31, ty = threadIdx.x >> 5;
  #pragma unroll
  for (int r = 0; r < 4; ++r) {
    int cc = ty + r*8;
    tl[cc][tx] = fusedT[((size_t)(b*CCH + c0 + cc))*JJ + j0 + tx];
  }
  __syncthreads();
  #pragma unroll
  for (int r = 0; r < 4; ++r) {
    int jj = ty + r*8;
    out[((size_t)(b*JJ + j0 + jj))*CCH + c0 + tx] = tl[tx][jj];
  }
}

extern "C" void kernel_launch(void* const* d_in, const int* in_sizes, int n_in,
                              void* d_out, int out_size, void* d_ws, size_t ws_size,
                              hipStream_t stream) {
  const float* feat   = (const float*)d_in[0];
  const float* kp     = (const float*)d_in[1];
  const float* w_off1 = (const float*)d_in[2];
  const float* b_off1 = (const float*)d_in[3];
  const float* w_off2 = (const float*)d_in[4];
  const float* b_off2 = (const float*)d_in[5];
  const float* w_att1 = (const float*)d_in[6];
  const float* b_att1 = (const float*)d_in[7];
  const float* w_att2 = (const float*)d_in[8];
  const float* b_att2 = (const float*)d_in[9];
  float* out = (float*)d_out;

  // workspace layout (floats):
  //   seedbuf : 0          .. 4194304   (reused as fusedT after k_head)
  //   part    : 4194304    .. 6291456   (2 c-halves of hidden partials)
  //   grids   : 6291456    .. 6324224
  //   attw    : 6324224    .. 6340608   (~24.2 MB total)
  float* ws      = (float*)d_ws;
  float* seedbuf = ws;
  float* part    = ws + (size_t)4194304;
  float* grids   = ws + (size_t)6291456;
  float* attwb   = ws + (size_t)6324224;

  k_seed<<<dim3(CCH, BB), 256, 0, stream>>>(feat, kp, seedbuf);
  k_mlp <<<dim3(JJ/JT, 2, BB), 256, 0, stream>>>(seedbuf, w_off1, w_att1, part);
  k_head<<<dim3(JJ/JT, BB), 256, 0, stream>>>(part, kp, b_off1, w_off2, b_off2,
                                              b_att1, w_att2, b_att2, grids, attwb);
  k_fuse<<<dim3(CCH, BB), 256, 0, stream>>>(feat, grids, attwb, seedbuf /*fusedT*/);
  k_tr  <<<dim3(CCH/32, JJ/32, BB), 256, 0, stream>>>(seedbuf, out);
}